// Round 5
// baseline (471.043 us; speedup 1.0000x reference)
//
#include <hip/hip_runtime.h>
#include <math.h>

namespace {
constexpr int D     = 192;
constexpr int HW    = 256 * 512;   // 131072 = 2^17
constexpr int TOTAL = 2 * HW;      // 262144 pixels
constexpr unsigned ROWB = (unsigned)HW * 4u;   // bytes per depth slice (512 KB)

// Correctly-rounded s/5 in 3 ops (Markstein): bit-exact vs IEEE s/5.0f for
// all normal s >= 0 (our s in [0,5)).
__device__ __forceinline__ float div5(float s) {
    const float c = 0.2f;
    float q = s * c;
    float r = __builtin_fmaf(-5.0f, q, s);
    return __builtin_fmaf(r, c, q);
}

// Uniform SGPR base + 32-bit byte offset -> global_load v, voff, s[base]
__device__ __forceinline__ float ldx(const float* __restrict__ xn, unsigned bo) {
    return *reinterpret_cast<const float*>(
               reinterpret_cast<const char*>(xn) + bo);
}

__device__ __forceinline__ bool in_range(int d, int lo, unsigned wd) {
    return (unsigned)(d - lo) <= wd;
}

// Streaming modal-mask state machine, bit-exact vs the numpy reference.
// (Identical to the verified 139 us round-0 kernel.)
struct Machine {
    float bprev, maxv;
    int   index, last_fall, index_l, index_r;
    bool  r_found;

    __device__ __forceinline__ void init() {
        bprev = 1.0f;          // "ones" prepend: diff at d=0 is b0 - 1 < 0 -> fall
        maxv  = -INFINITY;
        index = 0; last_fall = 0; index_l = 0;
        index_r = D - 1;       // default: rise at virtual position D (append ones)
        r_found = false;
    }

    __device__ __forceinline__ void step(int d, float b) {
        float diff = b - bprev;
        bool fall  = diff < 0.0f;
        last_fall  = fall ? d : last_fall;               // strict fall
        bool am    = b > maxv;                           // first-occurrence argmax
        maxv       = am ? b : maxv;
        index      = am ? d : index;
        index_l    = am ? last_fall : index_l;           // last fall <= new argmax
        bool rise  = (diff > 0.0f) & (!r_found) & (!am); // first strict rise AFTER argmax
        index_r    = am ? (D - 1) : (rise ? (d - 1) : index_r);
        r_found    = am ? false : (r_found | rise);
        bprev      = b;
    }

    __device__ __forceinline__ void finish(int& lo, unsigned& wd) const {
        int r = min(index_r - index, index - index_l);
        int t = 2 * index - index_r - index_l;
        bool valid = (t > -3) && (t < 3);
        lo = valid ? index_l : (index - r);
        int hi = valid ? index_r : (index + r);
        wd = (unsigned)(hi - lo);
    }
};

// Load chunk c (8 consecutive depths) from byte base vo4 (= hw4 + OFS*ROWB).
// NG < 8 zero-fills the tail (absolute depth >= D guard, last chunk of the
// lookahead stream only: depths 192,193 are reference zero-padding AND would
// read past image 1's buffer end).
template<int NG>
__device__ __forceinline__ void ld8(const float* __restrict__ xn, unsigned vo4,
                                    int c, float (&buf)[8]) {
    #pragma unroll
    for (int j = 0; j < 8; ++j)
        buf[j] = (j < NG) ? ldx(xn, vo4 + (unsigned)(8 * c + j) * ROWB) : 0.0f;
}

// 24 chunks of 8 depths, SIX-buffer rotating software pipeline: constant
// FIVE-chunk load->use distance (~40 steps of VALU between issue and wait),
// covering the ~900 cyc HBM-miss latency that capped the 3-buffer version at
// 49% VALUBusy. In-flight data: 48 VGPRs; total demand ~90 -- funded by the
// waves_per_eu(4,4) clamp below (budget 128), which the grid already pins.
template<int LASTN, typename F>
__device__ __forceinline__ void stream24(const float* __restrict__ xn,
                                         unsigned vo4, F&& f) {
    float A[8], B[8], C[8], Dv[8], E[8], Fv[8];
    ld8<8>(xn, vo4, 0, A);
    ld8<8>(xn, vo4, 1, B);
    ld8<8>(xn, vo4, 2, C);
    ld8<8>(xn, vo4, 3, Dv);
    ld8<8>(xn, vo4, 4, E);
    ld8<8>(xn, vo4, 5, Fv);
    int d = 0;
    auto comp = [&](float (&buf)[8]) {
        #pragma unroll
        for (int j = 0; j < 8; ++j) { f(d, buf[j]); ++d; }
    };
    // g=0: compute chunks 0-5, issue 6-11
    comp(A);  ld8<8>(xn, vo4, 6, A);
    comp(B);  ld8<8>(xn, vo4, 7, B);
    comp(C);  ld8<8>(xn, vo4, 8, C);
    comp(Dv); ld8<8>(xn, vo4, 9, Dv);
    comp(E);  ld8<8>(xn, vo4, 10, E);
    comp(Fv); ld8<8>(xn, vo4, 11, Fv);
    // g=1: compute 6-11, issue 12-17
    comp(A);  ld8<8>(xn, vo4, 12, A);
    comp(B);  ld8<8>(xn, vo4, 13, B);
    comp(C);  ld8<8>(xn, vo4, 14, C);
    comp(Dv); ld8<8>(xn, vo4, 15, Dv);
    comp(E);  ld8<8>(xn, vo4, 16, E);
    comp(Fv); ld8<8>(xn, vo4, 17, Fv);
    // g=2: compute 12-17, issue 18-23 (23 tail-guarded in lookahead mode)
    comp(A);  ld8<8>(xn, vo4, 18, A);
    comp(B);  ld8<8>(xn, vo4, 19, B);
    comp(C);  ld8<8>(xn, vo4, 20, C);
    comp(Dv); ld8<8>(xn, vo4, 21, Dv);
    comp(E);  ld8<8>(xn, vo4, 22, E);
    comp(Fv); ld8<LASTN>(xn, vo4, 23, Fv);
    // drain: compute 18-23
    comp(A); comp(B); comp(C); comp(Dv); comp(E); comp(Fv);
}
} // namespace

// waves_per_eu(4,4): pin occupancy target to EXACTLY the 4 waves/SIMD the
// 4096-wave grid provides. This both sets the VGPR budget to 128 AND stops
// the scheduler's occupancy-raising stages. Evidence it's needed:
//   - launch_bounds(256,4) alone: allocator shrank to 64 VGPR (its default
//     8-wave target) and spilled the 6-buffer pipeline -> WRITE_SIZE 290 MB
//     of scratch, 275 us (round 4).
//   - launch_bounds(256,8): collapsed to 32 VGPR, 280 MB scratch (round 2).
extern "C" __global__ void
__attribute__((amdgpu_flat_work_group_size(256, 256), amdgpu_waves_per_eu(4, 4)))
dme_kernel(const float* __restrict__ x, float* __restrict__ out)
{
    // n is block-uniform: 512 blocks per image -> base pointer lives in SGPRs.
    const int n  = blockIdx.x >> 9;
    const int hw = ((blockIdx.x & 511) << 8) | threadIdx.x;
    const float* __restrict__ xn = x + (size_t)n * ((size_t)D * HW);
    const unsigned hw4 = (unsigned)hw * 4u;

    const float x0 = ldx(xn, hw4);
    const float x1 = ldx(xn, hw4 + ROWB);

    // ================= pass 1: modal mask of blur(x) =================
    Machine m1; m1.init();
    {
        float w0 = 0.f, w1 = 0.f, w2 = x0, w3 = x1;
        stream24<6>(xn, hw4 + 2u * ROWB, [&](int d, float xv) {
            // exact left-to-right window sum, matching reference add order
            float s = w0 + w1; s += w2; s += w3; s += xv;
            m1.step(d, div5(s));
            w0 = w1; w1 = w2; w2 = w3; w3 = xv;
        });
    }
    int lo1; unsigned wd1; m1.finish(lo1, wd1);

    // ====== pass 2: modal mask of blur(x)*~mask1, plus y-sums ======
    Machine m2; m2.init();
    float sum_y = 0.f, wsum_y = 0.f;
    {
        float w0 = 0.f, w1 = 0.f, w2 = x0, w3 = x1;
        stream24<6>(xn, hw4 + 2u * ROWB, [&](int d, float xv) {
            float s = w0 + w1; s += w2; s += w3; s += xv;
            float b = div5(s);
            bool in1 = in_range(d, lo1, wd1);
            m2.step(d, in1 ? 0.0f : b);          // x_blur2 = x_blur * ~mask1
            float xm = in1 ? w2 : 0.0f;          // y = x*mask1; x[d] == w2
            sum_y += xm;
            wsum_y = __builtin_fmaf(xm, (float)d, wsum_y);
            w0 = w1; w1 = w2; w2 = w3; w3 = xv;
        });
    }
    int lo2; unsigned wd2; m2.finish(lo2, wd2);

    // ========= pass 3: z-sums (z = x * ~mask1 * mask2nd) =========
    float sum_z = 0.f, wsum_z = 0.f;
    {
        stream24<8>(xn, hw4, [&](int d, float xv) {
            bool z = in_range(d, lo2, wd2) & !in_range(d, lo1, wd1);
            float xm = z ? xv : 0.0f;
            sum_z += xm;
            wsum_z = __builtin_fmaf(xm, (float)d, wsum_z);
        });
    }

    bool  v = (sum_y >= sum_z);
    float S = v ? sum_y  : sum_z;
    float W = v ? wsum_y : wsum_z;
    out[hw + n * HW] = W / S;    // == sum(xm*d)/sum(xm)
}

extern "C" void kernel_launch(void* const* d_in, const int* in_sizes, int n_in,
                              void* d_out, int out_size, void* d_ws, size_t ws_size,
                              hipStream_t stream)
{
    const float* x   = (const float*)d_in[0];
    float*       out = (float*)d_out;
    dim3 block(256), grid(TOTAL / 256);          // 1024 blocks, 16 waves/CU
    hipLaunchKernelGGL(dme_kernel, grid, block, 0, stream, x, out);
}

// Round 7
// 320.565 us; speedup vs baseline: 1.4694x; 1.4694x over previous
//
#include <hip/hip_runtime.h>
#include <math.h>

namespace {
constexpr int D     = 192;
constexpr int HW    = 256 * 512;   // 131072 = 2^17
constexpr int TOTAL = 2 * HW;      // 262144 pixels

// Correctly-rounded s/5 in 3 ops (Markstein): bit-exact vs IEEE s/5.0f for
// all normal s >= 0 (our s in [0,5)).
__device__ __forceinline__ float div5(float s) {
    const float c = 0.2f;
    float q = s * c;
    float r = __builtin_fmaf(-5.0f, q, s);
    return __builtin_fmaf(r, c, q);
}

__device__ __forceinline__ bool in_range(int d, int lo, unsigned width) {
    return (unsigned)(d - lo) <= width;
}

// Streaming modal-mask state machine, bit-exact vs the numpy reference.
// (Identical to the verified 139 us round-0 kernel.)
struct Machine {
    float bprev, maxv;
    int   index, last_fall, index_l, index_r;
    bool  r_found;

    __device__ __forceinline__ void init() {
        bprev = 1.0f;          // "ones" prepend: diff at d=0 is b0 - 1 < 0 -> fall
        maxv  = -INFINITY;
        index = 0; last_fall = 0; index_l = 0;
        index_r = D - 1;       // default: rise at virtual position D (append ones)
        r_found = false;
    }

    __device__ __forceinline__ void step(int d, float b) {
        float diff = b - bprev;
        bool fall  = diff < 0.0f;
        last_fall  = fall ? d : last_fall;               // strict fall
        bool am    = b > maxv;                           // first-occurrence argmax
        maxv       = am ? b : maxv;
        index      = am ? d : index;
        index_l    = am ? last_fall : index_l;           // last fall <= new argmax
        bool rise  = (diff > 0.0f) & (!r_found) & (!am); // first strict rise AFTER argmax
        index_r    = am ? (D - 1) : (rise ? (d - 1) : index_r);
        r_found    = am ? false : (r_found | rise);
        bprev      = b;
    }

    __device__ __forceinline__ void finish(int& lo, unsigned& wd) const {
        int r = min(index_r - index, index - index_l);
        int t = 2 * index - index_r - index_l;
        bool valid = (t > -3) && (t < 3);
        lo = valid ? index_l : (index - r);
        int hi = valid ? index_r : (index + r);
        wd = (unsigned)(hi - lo);
    }
};

// OFS=2: chunk c supplies x[8c+2+j] (the d+2 lookahead for the blur window).
template<int OFS>
__device__ __forceinline__ void loadc(const float* __restrict__ col, int c,
                                      float (&buf)[8]) {
    #pragma unroll
    for (int j = 0; j < 8; ++j)
        buf[j] = col[(size_t)(8 * c + OFS + j) * HW];
}
template<int OFS>
__device__ __forceinline__ void loadc_guard(const float* __restrict__ col, int c,
                                            float (&buf)[8]) {
    #pragma unroll
    for (int j = 0; j < 8; ++j) {
        int idx = 8 * c + OFS + j;
        buf[j] = (idx < D) ? col[(size_t)idx * HW] : 0.0f;
    }
}

// 24 chunks of 8 depths, 3-buffer rotating software pipeline with a constant
// TWO-chunk load->use distance. This is the verified round-0 configuration:
// 64 VGPR, zero scratch. Deeper pipelines (6-buffer) were tried twice with
// launch_bounds/waves_per_eu funding -- the allocator refused >64 VGPR both
// times and spilled 290 MB/dispatch to scratch. Do not re-attempt in VGPRs.
template<int OFS, typename F>
__device__ __forceinline__ void stream24(const float* __restrict__ col, F&& f) {
    float A[8], B[8], C[8];
    loadc<OFS>(col, 0, A);
    loadc<OFS>(col, 1, B);
    loadc<OFS>(col, 2, C);
    int d = 0;
    auto comp = [&](float (&buf)[8]) {
        #pragma unroll
        for (int j = 0; j < 8; ++j) { f(d, buf[j]); ++d; }
    };
    for (int g = 0; g < 6; ++g) {          // chunks 3g..3g+2, issue 3g+3..3g+5
        comp(A); loadc<OFS>(col, 3 * g + 3, A);
        comp(B); loadc<OFS>(col, 3 * g + 4, B);
        comp(C); loadc<OFS>(col, 3 * g + 5, C);
    }
    // g == 6: computes 18..20, issues 21,22 plain; 23 needs the OOB guard
    // only in lookahead mode (indices 186..193; 192,193 -> 0).
    comp(A); loadc<OFS>(col, 21, A);
    comp(B); loadc<OFS>(col, 22, B);
    comp(C);
    if (OFS == 2) loadc_guard<OFS>(col, 23, C);
    else          loadc<OFS>(col, 23, C);
    // g == 7: drain
    comp(A); comp(B); comp(C);
}
} // namespace

extern "C" __global__ void __launch_bounds__(256, 4)
dme_kernel(const float* __restrict__ x, float* __restrict__ out)
{
    // n is block-uniform: 512 blocks per image -> base pointer lives in SGPRs.
    const int n  = blockIdx.x >> 9;
    const int hw = ((blockIdx.x & 511) << 8) | threadIdx.x;
    const float* __restrict__ col = x + (size_t)n * (size_t)(D * HW) + hw;

    const float x0 = col[0];
    const float x1 = col[HW];

    // ================= pass 1: modal mask of blur(x) =================
    Machine m1; m1.init();
    {
        float w0 = 0.f, w1 = 0.f, w2 = x0, w3 = x1;
        stream24<2>(col, [&](int d, float xv) {
            // exact left-to-right window sum, matching reference add order
            float s = w0 + w1; s += w2; s += w3; s += xv;
            m1.step(d, div5(s));
            w0 = w1; w1 = w2; w2 = w3; w3 = xv;
        });
    }
    int lo1; unsigned wd1; m1.finish(lo1, wd1);

    // ====== pass 2: modal mask of blur(x)*~mask1, plus y-sums ======
    Machine m2; m2.init();
    float sum_y = 0.f, wsum_y = 0.f;
    {
        float w0 = 0.f, w1 = 0.f, w2 = x0, w3 = x1;
        float fd = 0.0f;
        stream24<2>(col, [&](int d, float xv) {
            float s = w0 + w1; s += w2; s += w3; s += xv;
            float b = div5(s);
            bool in1 = in_range(d, lo1, wd1);
            m2.step(d, in1 ? 0.0f : b);          // x_blur2 = x_blur * ~mask1
            sum_y += in1 ? w2 : 0.f;             // y = x*mask1; x[d] == w2
            float t = in1 ? fd : 0.f;
            wsum_y = __builtin_fmaf(t, w2, wsum_y);
            w0 = w1; w1 = w2; w2 = w3; w3 = xv; fd += 1.0f;
        });
    }
    int lo2; unsigned wd2; m2.finish(lo2, wd2);

    // ========= pass 3: z-sums (z = x * ~mask1 * mask2nd) =========
    // z[d] == 0 outside [lo2, lo2+wd2]; the reference's jnp.sum adds those
    // zeros, and acc + 0.0f is an exact IEEE identity for our non-negative
    // accumulators (start 0.0, x >= 0) -- so folding ONLY the in-interval
    // depths in ascending d order is bit-identical to the full 192-depth
    // fold. [lo2, hi2] is provably within [0, D-1] (finish() algebra).
    // mask2 is a modal interval: typically ~3-8 wide on this data, so this
    // per-lane divergent loop replaces a 192-depth global re-stream (~1/3 of
    // the kernel's memory traffic) with ~max-lane-width iterations against
    // L2/L3-resident lines. Worst case (192) equals the old cost.
    float sum_z = 0.f, wsum_z = 0.f;
    {
        const int dend = lo2 + (int)wd2;
        for (int d = lo2; d <= dend; ++d) {
            float xv = col[(size_t)d * HW];
            bool  zz = !in_range(d, lo1, wd1);
            float xm = zz ? xv : 0.0f;
            sum_z += xm;
            wsum_z = __builtin_fmaf(xm, (float)d, wsum_z);
        }
    }

    bool  v = (sum_y >= sum_z);
    float S = v ? sum_y  : sum_z;
    float W = v ? wsum_y : wsum_z;
    out[hw + n * HW] = W / S;    // == sum(xm*d)/sum(xm)
}

extern "C" void kernel_launch(void* const* d_in, const int* in_sizes, int n_in,
                              void* d_out, int out_size, void* d_ws, size_t ws_size,
                              hipStream_t stream)
{
    const float* x   = (const float*)d_in[0];
    float*       out = (float*)d_out;
    dim3 block(256), grid(TOTAL / 256);          // 1024 blocks, 16 waves/CU
    hipLaunchKernelGGL(dme_kernel, grid, block, 0, stream, x, out);
}